// Round 3
// baseline (178.114 us; speedup 1.0000x reference)
//
#include <hip/hip_runtime.h>
#include <hip/hip_bf16.h>

// ON-LSTM cell fused, R3: 256x256 8-phase counted-vmcnt schedule (T2+T3+T4+T5).
// gates = [x|hx] @ [W_ih|W_hh]^T + b  via bf16 MFMA; cumsoftmax + LSTM fused.
// Block = 256 batch rows x 64 h-cols (one chunk) x 4 gates (gate-interleaved
// cols so o/c/i/f of (b,h) are lane-local). 8 waves (2M x 4N), BK=64,
// double-buffered 128 KiB LDS, 1 half-tile staged per phase, vmcnt(6) at
// phases 4/8 only.

#define B_ROWS 8192
#define IN_DIM 1024
#define H_DIM  1024
#define NCHUNK 16
#define K_TOT  2048

#define BM   256
#define BN   256
#define BK   64
#define NKT  (K_TOT / BK)   // 32 K-tiles, 16 iterations x 2
#define THREADS 512

#define A_PACK_BYTES ((size_t)B_ROWS * K_TOT * 2)        // 32 MiB
#define W_PACK_BYTES ((size_t)16 * 256 * K_TOT * 2)      // 16 MiB

typedef __attribute__((ext_vector_type(4))) float  f32x4;
typedef __bf16 bf16x8 __attribute__((ext_vector_type(8)));

__device__ __forceinline__ float sigmoidf_(float x) {
    return 1.0f / (1.0f + __expf(-x));
}
__device__ __forceinline__ float tanhf_(float x) {
    float e = __expf(-2.0f * fabsf(x));
    float t = (1.0f - e) / (1.0f + e);
    return copysignf(t, x);
}

__device__ __forceinline__ void gload16(const __bf16* gsrc, __bf16* lds_dst) {
    __builtin_amdgcn_global_load_lds(
        (const __attribute__((address_space(1))) unsigned int*)gsrc,
        (__attribute__((address_space(3))) unsigned int*)lds_dst, 16, 0, 0);
}

__device__ __forceinline__ bf16x8 cvt8(f32x4 v0, f32x4 v1) {
    bf16x8 o;
    o[0] = (__bf16)v0.x; o[1] = (__bf16)v0.y; o[2] = (__bf16)v0.z; o[3] = (__bf16)v0.w;
    o[4] = (__bf16)v1.x; o[5] = (__bf16)v1.y; o[6] = (__bf16)v1.z; o[7] = (__bf16)v1.w;
    return o;
}

// ---- pack [x | hx] -> bf16 Abf[8192][2048] ----
__global__ __launch_bounds__(256)
void pack_A(const float* __restrict__ x, const float* __restrict__ hx,
            __bf16* __restrict__ Abf)
{
    int idx = blockIdx.x * 256 + threadIdx.x;
    int row = idx >> 8;
    int c8  = (idx & 255) << 3;
    const float* src = (c8 < IN_DIM)
        ? (x  + (size_t)row * IN_DIM + c8)
        : (hx + (size_t)row * IN_DIM + (c8 - IN_DIM));
    f32x4 v0 = *reinterpret_cast<const f32x4*>(src);
    f32x4 v1 = *reinterpret_cast<const f32x4*>(src + 4);
    *reinterpret_cast<bf16x8*>(Abf + (size_t)row * K_TOT + c8) = cvt8(v0, v1);
}

// ---- pack W -> bf16 Wp[bh=16][n=256][2048] (gate-interleaved cols) ----
// tile col n: gate g=(n>>4)&3, h-col j=(n>>6)*16+(n&15); weight row g*1024+bh*64+j
__global__ __launch_bounds__(256)
void pack_W(const float* __restrict__ W_ih, const float* __restrict__ W_hh,
            __bf16* __restrict__ Wp)
{
    int idx = blockIdx.x * 256 + threadIdx.x;   // 16*256*256 total
    int k8  = (idx & 255) << 3;
    int n   = (idx >> 8) & 255;
    int bh  = idx >> 16;
    int g   = (n >> 4) & 3;
    int j   = (n >> 6) * 16 + (n & 15);
    int wr  = g * H_DIM + bh * 64 + j;
    const float* src = (k8 < IN_DIM)
        ? (W_ih + (size_t)wr * IN_DIM + k8)
        : (W_hh + (size_t)wr * IN_DIM + (k8 - IN_DIM));
    f32x4 v0 = *reinterpret_cast<const f32x4*>(src);
    f32x4 v1 = *reinterpret_cast<const f32x4*>(src + 4);
    *reinterpret_cast<bf16x8*>(Wp + ((size_t)bh * 256 + n) * K_TOT + k8) = cvt8(v0, v1);
}

// stage one 128x64 half-tile: 2 x global_load_lds(16B)/thread, linear LDS dest,
// inverse-swizzled global source (swz: elem k ^= (row&7)<<3).
__device__ __forceinline__ void stage_half(const __bf16* __restrict__ gbase, int kb,
                                           __bf16* lbase, int row0, int tid) {
    #pragma unroll
    for (int i = 0; i < 2; ++i) {
        int e   = i * 4096 + tid * 8;
        int row = row0 + (e >> 6);
        int kd  = e & 63;
        gload16(gbase + (size_t)row * K_TOT + kb + (kd ^ ((row & 7) << 3)), lbase + e);
    }
}

#define PH(q) \
    __builtin_amdgcn_s_setprio(1); \
    _Pragma("unroll") \
    for (int fn = 0; fn < 4; ++fn) { \
        acc[2*(q)][fn]   = __builtin_amdgcn_mfma_f32_16x16x32_bf16(af[2*(q)][0],   bfr[fn][0], acc[2*(q)][fn],   0,0,0); \
        acc[2*(q)][fn]   = __builtin_amdgcn_mfma_f32_16x16x32_bf16(af[2*(q)][1],   bfr[fn][1], acc[2*(q)][fn],   0,0,0); \
        acc[2*(q)+1][fn] = __builtin_amdgcn_mfma_f32_16x16x32_bf16(af[2*(q)+1][0], bfr[fn][0], acc[2*(q)+1][fn], 0,0,0); \
        acc[2*(q)+1][fn] = __builtin_amdgcn_mfma_f32_16x16x32_bf16(af[2*(q)+1][1], bfr[fn][1], acc[2*(q)+1][fn], 0,0,0); \
    } \
    __builtin_amdgcn_s_setprio(0);

#define PHASE(q, ...) { \
    __VA_ARGS__; \
    asm volatile("" ::: "memory"); \
    __builtin_amdgcn_s_barrier(); \
    asm volatile("s_waitcnt lgkmcnt(0)" ::: "memory"); \
    __builtin_amdgcn_sched_barrier(0); \
    PH(q) \
    asm volatile("" ::: "memory"); \
    __builtin_amdgcn_s_barrier(); \
    asm volatile("" ::: "memory"); \
}

#define PHASE_V(q, ...) { \
    __VA_ARGS__; \
    asm volatile("" ::: "memory"); \
    __builtin_amdgcn_s_barrier(); \
    asm volatile("s_waitcnt lgkmcnt(0)" ::: "memory"); \
    __builtin_amdgcn_sched_barrier(0); \
    PH(q) \
    asm volatile("s_waitcnt vmcnt(6)" ::: "memory"); \
    __builtin_amdgcn_s_barrier(); \
    asm volatile("" ::: "memory"); \
}

#define LOAD_FRAGS(As, Bs) { \
    _Pragma("unroll") \
    for (int fn = 0; fn < 4; ++fn) { \
        int br = wcol + fn * 16 + lr; \
        bfr[fn][0] = *reinterpret_cast<const bf16x8*>(&(Bs)[br * 64 + ((lh*8)      ^ ((br & 7) << 3))]); \
        bfr[fn][1] = *reinterpret_cast<const bf16x8*>(&(Bs)[br * 64 + ((32 + lh*8) ^ ((br & 7) << 3))]); \
    } \
    _Pragma("unroll") \
    for (int mm = 0; mm < 8; ++mm) { \
        int ar = wrow + mm * 16 + lr; \
        af[mm][0] = *reinterpret_cast<const bf16x8*>(&(As)[ar * 64 + ((lh*8)      ^ ((ar & 7) << 3))]); \
        af[mm][1] = *reinterpret_cast<const bf16x8*>(&(As)[ar * 64 + ((32 + lh*8) ^ ((ar & 7) << 3))]); \
    } }

__global__ __launch_bounds__(THREADS, 2)
void onlstm_gemm8(const __bf16* __restrict__ Abf, const __bf16* __restrict__ Wp,
                  const float* __restrict__ cx,
                  const float* __restrict__ input_floor,
                  const float* __restrict__ forget_floor,
                  const float* __restrict__ b_ih, const float* __restrict__ b_hh,
                  float* __restrict__ out)
{
    // LDS: [buf0: A(16K elem) B(16K)][buf1: A B]  halves of 8192 elems each
    __shared__ __align__(16) __bf16 lds[65536];          // 128 KiB
    __shared__ float ci_s[BM], cf_s[BM], bias_s[BN];

    const int tid = threadIdx.x;
    // bijective XCD swizzle: 512 blocks, 64 per XCD
    const int n0  = blockIdx.x;
    const int swz = (n0 & 7) * 64 + (n0 >> 3);
    const int bh  = swz >> 5;          // 0..15  (chunk / 64-col h tile)
    const int bm  = swz & 31;          // 0..31  (256-row tile)
    const int h0  = bh * 64;
    const int nc  = bh;                // chunk index

    // ---- prologue: bias + per-row cumulative-softmax master gates ----
    if (tid < BM) {
        {
            int g = (tid >> 4) & 3;
            int j = (tid >> 6) * 16 + (tid & 15);
            int wr = g * H_DIM + h0 + j;
            bias_s[tid] = b_ih[wr] + b_hh[wr];
        }
        int b = bm * BM + tid;
        const int off = (nc < 8) ? 0 : 8;
        const int ic  = (nc < 8) ? nc : (nc - 8);
        const float* pin = input_floor  + (size_t)b * NCHUNK + off;
        const float* pfg = forget_floor + (size_t)b * NCHUNK + off;
        float vi[8], vf[8];
        float mi = -1e30f, mf = -1e30f;
        #pragma unroll
        for (int t = 0; t < 8; ++t) {
            vi[t] = pin[t]; vf[t] = pfg[t];
            mi = fmaxf(mi, vi[t]); mf = fmaxf(mf, vf[t]);
        }
        float si = 0.f, sf = 0.f;
        #pragma unroll
        for (int t = 0; t < 8; ++t) {
            vi[t] = __expf(vi[t] - mi); vf[t] = __expf(vf[t] - mf);
            si += vi[t]; sf += vf[t];
        }
        float pi = 0.f, pf = 0.f;
        #pragma unroll
        for (int t = 0; t < 8; ++t) { if (t <= ic) { pi += vi[t]; pf += vf[t]; } }
        float suf_i = si - pi + vi[ic];
        float suf_f = sf - pf + vf[ic];
        float civ, cfv;
        if (nc < 8) { civ = pi / si;    cfv = suf_f / sf; }
        else        { civ = suf_i / si; cfv = pf / sf;    }
        ci_s[tid] = civ; cf_s[tid] = cfv;
    }

    const __bf16* Arow = Abf + (size_t)(bm * BM) * K_TOT;
    const __bf16* Wblk = Wp  + (size_t)bh * 256 * K_TOT;
    __bf16* const A0p = lds;
    __bf16* const B0p = lds + 16384;
    __bf16* const A1p = lds + 32768;
    __bf16* const B1p = lds + 49152;

    // prologue staging: tile0 full (buf0), tile1 A0,A1,B0 (buf1) -> 14 vm ops
    stage_half(Arow, 0,  A0p,        0,   tid);
    stage_half(Arow, 0,  A0p + 8192, 128, tid);
    stage_half(Wblk, 0,  B0p,        0,   tid);
    stage_half(Wblk, 0,  B0p + 8192, 128, tid);
    stage_half(Arow, BK, A1p,        0,   tid);
    stage_half(Arow, BK, A1p + 8192, 128, tid);
    stage_half(Wblk, BK, B1p,        0,   tid);
    asm volatile("s_waitcnt lgkmcnt(0)" ::: "memory");   // ci/bias ds_writes done
    asm volatile("s_waitcnt vmcnt(6)"   ::: "memory");   // tile0 complete
    __builtin_amdgcn_s_barrier();
    asm volatile("" ::: "memory");

    f32x4  acc[8][4];
    #pragma unroll
    for (int i = 0; i < 8; ++i)
        #pragma unroll
        for (int j = 0; j < 4; ++j) acc[i][j] = (f32x4){0.f, 0.f, 0.f, 0.f};
    bf16x8 af[8][2];
    bf16x8 bfr[4][2];

    const int l    = tid & 63;
    const int wid  = tid >> 6;        // 0..7
    const int wr   = wid >> 2;        // 0..1  (M)
    const int wc   = wid & 3;         // 0..3  (N)
    const int lr   = l & 15;
    const int lh   = l >> 4;
    const int wrow = wr * 128;
    const int wcol = wc * 64;

    #pragma unroll 1
    for (int it = 0; it < NKT / 2; ++it) {
        const int t = 2 * it;
        // ---- K-tile t (buf0) ----
        LOAD_FRAGS(A0p, B0p);
        PHASE  (0, stage_half(Wblk, ((t+1) & 31) * BK, B1p + 8192, 128, tid));  // (t+1).B1
        PHASE  (1, stage_half(Arow, ((t+2) & 31) * BK, A0p,        0,   tid));  // (t+2).A0
        PHASE  (2, stage_half(Arow, ((t+2) & 31) * BK, A0p + 8192, 128, tid));  // (t+2).A1
        PHASE_V(3, stage_half(Wblk, ((t+2) & 31) * BK, B0p,        0,   tid));  // (t+2).B0
        // ---- K-tile t+1 (buf1) ----
        LOAD_FRAGS(A1p, B1p);
        PHASE  (0, stage_half(Wblk, ((t+2) & 31) * BK, B0p + 8192, 128, tid));  // (t+2).B1
        PHASE  (1, stage_half(Arow, ((t+3) & 31) * BK, A1p,        0,   tid));  // (t+3).A0
        PHASE  (2, stage_half(Arow, ((t+3) & 31) * BK, A1p + 8192, 128, tid));  // (t+3).A1
        PHASE_V(3, stage_half(Wblk, ((t+3) & 31) * BK, B1p,        0,   tid));  // (t+3).B0
    }
    asm volatile("s_waitcnt vmcnt(0)" ::: "memory");

    // ---- epilogue: all 4 gates of (b,h) lane-local (fn = gate) ----
    const size_t CY_OFF = (size_t)B_ROWS * H_DIM;
    const int hcol = h0 + wc * 16 + lr;
    #pragma unroll
    for (int m = 0; m < 8; ++m) {
        #pragma unroll
        for (int r = 0; r < 4; ++r) {
            int rt = wrow + m * 16 + lh * 4 + r;
            int b  = bm * BM + rt;
            float civ = ci_s[rt], cfv = cf_s[rt];
            float ovl = cfv * civ;
            float og = acc[m][0][r] + bias_s[wcol + lr];
            float cg = acc[m][1][r] + bias_s[wcol + 16 + lr];
            float ig = acc[m][2][r] + bias_s[wcol + 32 + lr];
            float fg = acc[m][3][r] + bias_s[wcol + 48 + lr];
            float i_s = sigmoidf_(ig);
            float f_s = sigmoidf_(fg);
            float c_t = tanhf_(cg);
            float o_s = sigmoidf_(og);
            float fq = f_s * ovl + (cfv - ovl);
            float iq = i_s * ovl + (civ - ovl);
            float cxv = cx[(size_t)b * H_DIM + hcol];
            float cyv = fq * cxv + iq * c_t;
            float hyv = o_s * tanhf_(cyv);
            out[(size_t)b * H_DIM + hcol] = hyv;
            out[CY_OFF + (size_t)b * H_DIM + hcol] = cyv;
        }
    }
}

extern "C" void kernel_launch(void* const* d_in, const int* in_sizes, int n_in,
                              void* d_out, int out_size, void* d_ws, size_t ws_size,
                              hipStream_t stream) {
    const float* x            = (const float*)d_in[0];
    const float* hx           = (const float*)d_in[1];
    const float* cx           = (const float*)d_in[2];
    const float* input_floor  = (const float*)d_in[3];
    const float* forget_floor = (const float*)d_in[4];
    const float* W_ih         = (const float*)d_in[5];
    const float* b_ih         = (const float*)d_in[6];
    const float* W_hh         = (const float*)d_in[7];
    const float* b_hh         = (const float*)d_in[8];
    float* out = (float*)d_out;

    __bf16* Abf = (__bf16*)d_ws;
    __bf16* Wp  = (__bf16*)((char*)d_ws + A_PACK_BYTES);
    pack_A<<<B_ROWS, 256, 0, stream>>>(x, hx, Abf);
    pack_W<<<16 * 256, 256, 0, stream>>>(W_ih, W_hh, Wp);
    onlstm_gemm8<<<512, THREADS, 0, stream>>>(
        Abf, Wp, cx, input_floor, forget_floor, b_ih, b_hh, out);
}

// Round 4
// 160.365 us; speedup vs baseline: 1.1107x; 1.1107x over previous
//
#include <hip/hip_runtime.h>
#include <hip/hip_bf16.h>

// ON-LSTM cell fused, R4: faithful 256x256 8-phase schedule — per-phase
// {ds_read frags + 1 half-tile stage + barrier + lgkm(0) + 16 MFMA + barrier},
// counted vmcnt(4) once per K-tile, setprio around MFMA, XCD swizzle with
// A-panels L2-resident. gates = [x|hx]@[W_ih|W_hh]^T + b; cumsoftmax+LSTM fused.

#define B_ROWS 8192
#define IN_DIM 1024
#define H_DIM  1024
#define NCHUNK 16
#define K_TOT  2048

#define BM   256
#define BN   256
#define BK   64
#define NKT  (K_TOT / BK)   // 32 K-tiles
#define THREADS 512

#define A_PACK_BYTES ((size_t)B_ROWS * K_TOT * 2)        // 32 MiB
#define W_PACK_BYTES ((size_t)16 * 256 * K_TOT * 2)      // 16 MiB

typedef __attribute__((ext_vector_type(4))) float  f32x4;
typedef __bf16 bf16x8 __attribute__((ext_vector_type(8)));

__device__ __forceinline__ float sigmoidf_(float x) {
    return 1.0f / (1.0f + __expf(-x));
}
__device__ __forceinline__ float tanhf_(float x) {
    float e = __expf(-2.0f * fabsf(x));
    float t = (1.0f - e) / (1.0f + e);
    return copysignf(t, x);
}

__device__ __forceinline__ void gload16(const __bf16* gsrc, __bf16* lds_dst) {
    __builtin_amdgcn_global_load_lds(
        (const __attribute__((address_space(1))) unsigned int*)gsrc,
        (__attribute__((address_space(3))) unsigned int*)lds_dst, 16, 0, 0);
}

__device__ __forceinline__ bf16x8 cvt8(f32x4 v0, f32x4 v1) {
    bf16x8 o;
    o[0] = (__bf16)v0.x; o[1] = (__bf16)v0.y; o[2] = (__bf16)v0.z; o[3] = (__bf16)v0.w;
    o[4] = (__bf16)v1.x; o[5] = (__bf16)v1.y; o[6] = (__bf16)v1.z; o[7] = (__bf16)v1.w;
    return o;
}

// ---- pack [x | hx] -> bf16 Abf[8192][2048] ----
__global__ __launch_bounds__(256)
void pack_A(const float* __restrict__ x, const float* __restrict__ hx,
            __bf16* __restrict__ Abf)
{
    int idx = blockIdx.x * 256 + threadIdx.x;
    int row = idx >> 8;
    int c8  = (idx & 255) << 3;
    const float* src = (c8 < IN_DIM)
        ? (x  + (size_t)row * IN_DIM + c8)
        : (hx + (size_t)row * IN_DIM + (c8 - IN_DIM));
    f32x4 v0 = *reinterpret_cast<const f32x4*>(src);
    f32x4 v1 = *reinterpret_cast<const f32x4*>(src + 4);
    *reinterpret_cast<bf16x8*>(Abf + (size_t)row * K_TOT + c8) = cvt8(v0, v1);
}

// ---- pack W -> bf16 Wp[bh=16][n=256][2048] (gate-interleaved cols) ----
// tile col n: gate g=(n>>4)&3, h-col j=(n>>6)*16+(n&15); weight row g*1024+bh*64+j
__global__ __launch_bounds__(256)
void pack_W(const float* __restrict__ W_ih, const float* __restrict__ W_hh,
            __bf16* __restrict__ Wp)
{
    int idx = blockIdx.x * 256 + threadIdx.x;   // 16*256*256 total
    int k8  = (idx & 255) << 3;
    int n   = (idx >> 8) & 255;
    int bh  = idx >> 16;
    int g   = (n >> 4) & 3;
    int j   = (n >> 6) * 16 + (n & 15);
    int wr  = g * H_DIM + bh * 64 + j;
    const float* src = (k8 < IN_DIM)
        ? (W_ih + (size_t)wr * IN_DIM + k8)
        : (W_hh + (size_t)wr * IN_DIM + (k8 - IN_DIM));
    f32x4 v0 = *reinterpret_cast<const f32x4*>(src);
    f32x4 v1 = *reinterpret_cast<const f32x4*>(src + 4);
    *reinterpret_cast<bf16x8*>(Wp + ((size_t)bh * 256 + n) * K_TOT + k8) = cvt8(v0, v1);
}

// stage one 128x64 half-tile: 2 x global_load_lds(16B)/thread, linear LDS dest,
// inverse-swizzled global source.
__device__ __forceinline__ void stage_half(const __bf16* __restrict__ gbase, int kb,
                                           __bf16* lbase, int row0, int tid) {
    #pragma unroll
    for (int i = 0; i < 2; ++i) {
        int e   = i * 4096 + tid * 8;
        int row = row0 + (e >> 6);
        int kd  = e & 63;
        gload16(gbase + (size_t)row * K_TOT + kb + (kd ^ ((row & 7) << 3)), lbase + e);
    }
}

#define SWZ(r, k) ((r) * 64 + ((k) ^ (((r) & 7) << 3)))

#define LDB(Bs) { \
    _Pragma("unroll") \
    for (int fn = 0; fn < 4; ++fn) { \
        int br = wcol + fn * 16 + lr; \
        bfr[fn][0] = *reinterpret_cast<const bf16x8*>(&(Bs)[SWZ(br, lh * 8)]); \
        bfr[fn][1] = *reinterpret_cast<const bf16x8*>(&(Bs)[SWZ(br, 32 + lh * 8)]); \
    } }

#define LDA(As, q) { \
    int ar = wrow + (q) * 32 + lr; \
    af[0][0] = *reinterpret_cast<const bf16x8*>(&(As)[SWZ(ar, lh * 8)]); \
    af[0][1] = *reinterpret_cast<const bf16x8*>(&(As)[SWZ(ar, 32 + lh * 8)]); \
    af[1][0] = *reinterpret_cast<const bf16x8*>(&(As)[SWZ(ar + 16, lh * 8)]); \
    af[1][1] = *reinterpret_cast<const bf16x8*>(&(As)[SWZ(ar + 16, 32 + lh * 8)]); \
    }

#define PH_PRE \
    asm volatile("" ::: "memory"); \
    __builtin_amdgcn_s_barrier(); \
    asm volatile("s_waitcnt lgkmcnt(0)" ::: "memory"); \
    __builtin_amdgcn_sched_barrier(0);

#define MF(q) { \
    __builtin_amdgcn_s_setprio(1); \
    _Pragma("unroll") \
    for (int fn = 0; fn < 4; ++fn) { \
        acc[2*(q)][fn]   = __builtin_amdgcn_mfma_f32_16x16x32_bf16(af[0][0], bfr[fn][0], acc[2*(q)][fn],   0,0,0); \
        acc[2*(q)][fn]   = __builtin_amdgcn_mfma_f32_16x16x32_bf16(af[0][1], bfr[fn][1], acc[2*(q)][fn],   0,0,0); \
        acc[2*(q)+1][fn] = __builtin_amdgcn_mfma_f32_16x16x32_bf16(af[1][0], bfr[fn][0], acc[2*(q)+1][fn], 0,0,0); \
        acc[2*(q)+1][fn] = __builtin_amdgcn_mfma_f32_16x16x32_bf16(af[1][1], bfr[fn][1], acc[2*(q)+1][fn], 0,0,0); \
    } \
    __builtin_amdgcn_s_setprio(0); \
    __builtin_amdgcn_sched_barrier(0); \
}

#define PH_POST \
    asm volatile("" ::: "memory"); \
    __builtin_amdgcn_s_barrier();

#define PH_POSTV \
    asm volatile("s_waitcnt vmcnt(4)" ::: "memory"); \
    __builtin_amdgcn_s_barrier();

__global__ __launch_bounds__(THREADS, 2)
void onlstm_gemm8(const __bf16* __restrict__ Abf, const __bf16* __restrict__ Wp,
                  const float* __restrict__ cx,
                  const float* __restrict__ input_floor,
                  const float* __restrict__ forget_floor,
                  const float* __restrict__ b_ih, const float* __restrict__ b_hh,
                  float* __restrict__ out)
{
    __shared__ __align__(16) __bf16 lds[65536];          // 128 KiB
    __shared__ float ci_s[BM], cf_s[BM], bias_s[BN];

    const int tid = threadIdx.x;
    // XCD swizzle: xcd = n0&7 owns bm in [4*xcd, 4*xcd+4) x all 16 bh
    // -> A working set 4 panels = 4 MiB = L2-resident per XCD.
    const int n0  = blockIdx.x;
    const int bm  = (n0 & 7) * 4 + ((n0 >> 3) & 3);   // 0..31
    const int bh  = n0 >> 5;                          // 0..15
    const int h0  = bh * 64;
    const int nc  = bh;

    // ---- prologue: bias + per-row cumulative-softmax master gates ----
    if (tid < BM) {
        {
            int g = (tid >> 4) & 3;
            int j = (tid >> 6) * 16 + (tid & 15);
            int wrr = g * H_DIM + h0 + j;
            bias_s[tid] = b_ih[wrr] + b_hh[wrr];
        }
        int b = bm * BM + tid;
        const int off = (nc < 8) ? 0 : 8;
        const int ic  = (nc < 8) ? nc : (nc - 8);
        const float* pin = input_floor  + (size_t)b * NCHUNK + off;
        const float* pfg = forget_floor + (size_t)b * NCHUNK + off;
        float vi[8], vf[8];
        float mi = -1e30f, mf = -1e30f;
        #pragma unroll
        for (int t = 0; t < 8; ++t) {
            vi[t] = pin[t]; vf[t] = pfg[t];
            mi = fmaxf(mi, vi[t]); mf = fmaxf(mf, vf[t]);
        }
        float si = 0.f, sf = 0.f;
        #pragma unroll
        for (int t = 0; t < 8; ++t) {
            vi[t] = __expf(vi[t] - mi); vf[t] = __expf(vf[t] - mf);
            si += vi[t]; sf += vf[t];
        }
        float pi = 0.f, pf = 0.f;
        #pragma unroll
        for (int t = 0; t < 8; ++t) { if (t <= ic) { pi += vi[t]; pf += vf[t]; } }
        float suf_i = si - pi + vi[ic];
        float suf_f = sf - pf + vf[ic];
        float civ, cfv;
        if (nc < 8) { civ = pi / si;    cfv = suf_f / sf; }
        else        { civ = suf_i / si; cfv = pf / sf;    }
        ci_s[tid] = civ; cf_s[tid] = cfv;
    }

    const __bf16* Arow = Abf + (size_t)(bm * BM) * K_TOT;
    const __bf16* Wblk = Wp  + (size_t)bh * 256 * K_TOT;
    __bf16* const A0p = lds;
    __bf16* const B0p = lds + 16384;
    __bf16* const A1p = lds + 32768;
    __bf16* const B1p = lds + 49152;

    // prologue staging: t0.A (A0p), t0.B (B0p), t1.B (B1p)  [t1.A staged in t0.p0/p1]
    stage_half(Arow, 0,  A0p,        0,   tid);
    stage_half(Arow, 0,  A0p + 8192, 128, tid);
    stage_half(Wblk, 0,  B0p,        0,   tid);
    stage_half(Wblk, 0,  B0p + 8192, 128, tid);
    stage_half(Wblk, BK, B1p,        0,   tid);
    stage_half(Wblk, BK, B1p + 8192, 128, tid);
    asm volatile("s_waitcnt lgkmcnt(0)" ::: "memory");
    asm volatile("s_waitcnt vmcnt(0)"   ::: "memory");
    __builtin_amdgcn_s_barrier();
    asm volatile("" ::: "memory");

    f32x4  acc[8][4];
    #pragma unroll
    for (int i = 0; i < 8; ++i)
        #pragma unroll
        for (int j = 0; j < 4; ++j) acc[i][j] = (f32x4){0.f, 0.f, 0.f, 0.f};
    bf16x8 af[2][2];
    bf16x8 bfr[4][2];

    const int l    = tid & 63;
    const int wid  = tid >> 6;        // 0..7
    const int wrw  = wid >> 2;        // 0..1  (M)
    const int wc   = wid & 3;         // 0..3  (N)
    const int lr   = l & 15;
    const int lh   = l >> 4;
    const int wrow = wrw * 128;
    const int wcol = wc * 64;

    #pragma unroll 1
    for (int it = 0; it < NKT / 2; ++it) {
        const int t = 2 * it;
        // ---- K-tile t (buf0) ----
        LDB(B0p); LDA(A0p, 0);
        stage_half(Arow, ((t + 1) & 31) * BK, A1p,        0,   tid);   // (t+1).A0
        PH_PRE; MF(0); PH_POST;
        LDA(A0p, 1);
        stage_half(Arow, ((t + 1) & 31) * BK, A1p + 8192, 128, tid);   // (t+1).A1
        PH_PRE; MF(1); PH_POST;
        LDA(A0p, 2);
        stage_half(Wblk, ((t + 2) & 31) * BK, B0p,        0,   tid);   // (t+2).B0
        PH_PRE; MF(2); PH_POST;
        LDA(A0p, 3);
        stage_half(Wblk, ((t + 2) & 31) * BK, B0p + 8192, 128, tid);   // (t+2).B1
        PH_PRE; MF(3); PH_POSTV;
        // ---- K-tile t+1 (buf1) ----
        LDB(B1p); LDA(A1p, 0);
        stage_half(Arow, ((t + 2) & 31) * BK, A0p,        0,   tid);   // (t+2).A0
        PH_PRE; MF(0); PH_POST;
        LDA(A1p, 1);
        stage_half(Arow, ((t + 2) & 31) * BK, A0p + 8192, 128, tid);   // (t+2).A1
        PH_PRE; MF(1); PH_POST;
        LDA(A1p, 2);
        stage_half(Wblk, ((t + 3) & 31) * BK, B1p,        0,   tid);   // (t+3).B0
        PH_PRE; MF(2); PH_POST;
        LDA(A1p, 3);
        stage_half(Wblk, ((t + 3) & 31) * BK, B1p + 8192, 128, tid);   // (t+3).B1
        PH_PRE; MF(3); PH_POSTV;
    }
    asm volatile("s_waitcnt vmcnt(0)" ::: "memory");

    // ---- epilogue: all 4 gates of (b,h) lane-local (fn = gate) ----
    const size_t CY_OFF = (size_t)B_ROWS * H_DIM;
    const int hcol = h0 + wc * 16 + lr;
    #pragma unroll
    for (int m = 0; m < 8; ++m) {
        #pragma unroll
        for (int r = 0; r < 4; ++r) {
            int rt = wrow + m * 16 + lh * 4 + r;
            int b  = bm * BM + rt;
            float civ = ci_s[rt], cfv = cf_s[rt];
            float ovl = cfv * civ;
            float og = acc[m][0][r] + bias_s[wcol + lr];
            float cg = acc[m][1][r] + bias_s[wcol + 16 + lr];
            float ig = acc[m][2][r] + bias_s[wcol + 32 + lr];
            float fg = acc[m][3][r] + bias_s[wcol + 48 + lr];
            float i_s = sigmoidf_(ig);
            float f_s = sigmoidf_(fg);
            float c_t = tanhf_(cg);
            float o_s = sigmoidf_(og);
            float fq = f_s * ovl + (cfv - ovl);
            float iq = i_s * ovl + (civ - ovl);
            float cxv = cx[(size_t)b * H_DIM + hcol];
            float cyv = fq * cxv + iq * c_t;
            float hyv = o_s * tanhf_(cyv);
            out[(size_t)b * H_DIM + hcol] = hyv;
            out[CY_OFF + (size_t)b * H_DIM + hcol] = cyv;
        }
    }
}

extern "C" void kernel_launch(void* const* d_in, const int* in_sizes, int n_in,
                              void* d_out, int out_size, void* d_ws, size_t ws_size,
                              hipStream_t stream) {
    const float* x            = (const float*)d_in[0];
    const float* hx           = (const float*)d_in[1];
    const float* cx           = (const float*)d_in[2];
    const float* input_floor  = (const float*)d_in[3];
    const float* forget_floor = (const float*)d_in[4];
    const float* W_ih         = (const float*)d_in[5];
    const float* b_ih         = (const float*)d_in[6];
    const float* W_hh         = (const float*)d_in[7];
    const float* b_hh         = (const float*)d_in[8];
    float* out = (float*)d_out;

    __bf16* Abf = (__bf16*)d_ws;
    __bf16* Wp  = (__bf16*)((char*)d_ws + A_PACK_BYTES);
    pack_A<<<B_ROWS, 256, 0, stream>>>(x, hx, Abf);
    pack_W<<<16 * 256, 256, 0, stream>>>(W_ih, W_hh, Wp);
    onlstm_gemm8<<<512, THREADS, 0, stream>>>(
        Abf, Wp, cx, input_floor, forget_floor, b_ih, b_hh, out);
}

// Round 5
// 157.484 us; speedup vs baseline: 1.1310x; 1.0183x over previous
//
#include <hip/hip_runtime.h>
#include <hip/hip_bf16.h>

// ON-LSTM cell fused, R5: 256x256 8-phase schedule, ONE barrier per phase
// ({frag ds_reads; stage; lgkm(0); [vmcnt(4)]; barrier; 16 MFMA}), both A
// halves staged at p0 (3-phase latency cover), B(t+2) at p1/p2, counted
// vmcnt(4) once per K-tile, k-outer MFMA ordering, fused pack kernel.

#define B_ROWS 8192
#define IN_DIM 1024
#define H_DIM  1024
#define NCHUNK 16
#define K_TOT  2048

#define BM   256
#define BN   256
#define BK   64
#define NKT  (K_TOT / BK)   // 32 K-tiles
#define THREADS 512

#define A_PACK_BYTES ((size_t)B_ROWS * K_TOT * 2)        // 32 MiB
#define W_PACK_BYTES ((size_t)16 * 256 * K_TOT * 2)      // 16 MiB

typedef __attribute__((ext_vector_type(4))) float  f32x4;
typedef __bf16 bf16x8 __attribute__((ext_vector_type(8)));

__device__ __forceinline__ float sigmoidf_(float x) {
    return 1.0f / (1.0f + __expf(-x));
}
__device__ __forceinline__ float tanhf_(float x) {
    float e = __expf(-2.0f * fabsf(x));
    float t = (1.0f - e) / (1.0f + e);
    return copysignf(t, x);
}

__device__ __forceinline__ void gload16(const __bf16* gsrc, __bf16* lds_dst) {
    __builtin_amdgcn_global_load_lds(
        (const __attribute__((address_space(1))) unsigned int*)gsrc,
        (__attribute__((address_space(3))) unsigned int*)lds_dst, 16, 0, 0);
}

__device__ __forceinline__ bf16x8 cvt8(f32x4 v0, f32x4 v1) {
    bf16x8 o;
    o[0] = (__bf16)v0.x; o[1] = (__bf16)v0.y; o[2] = (__bf16)v0.z; o[3] = (__bf16)v0.w;
    o[4] = (__bf16)v1.x; o[5] = (__bf16)v1.y; o[6] = (__bf16)v1.z; o[7] = (__bf16)v1.w;
    return o;
}

// ---- fused pack: blocks [0,8192) pack A rows; [8192,12288) pack W rows ----
// A: [x|hx] -> bf16 Abf[8192][2048].
// W: tile col n of block bh: gate g=(n>>4)&3, h j=(n>>6)*16+(n&15),
//    weight row g*1024 + bh*64 + j  ->  Wp[bh][n][2048].
__global__ __launch_bounds__(256)
void pack_AW(const float* __restrict__ x, const float* __restrict__ hx,
             const float* __restrict__ W_ih, const float* __restrict__ W_hh,
             __bf16* __restrict__ Abf, __bf16* __restrict__ Wp)
{
    const int bid = blockIdx.x;
    const int c8  = threadIdx.x << 3;
    if (bid < B_ROWS) {
        const float* src = (c8 < IN_DIM)
            ? (x  + (size_t)bid * IN_DIM + c8)
            : (hx + (size_t)bid * IN_DIM + (c8 - IN_DIM));
        f32x4 v0 = *reinterpret_cast<const f32x4*>(src);
        f32x4 v1 = *reinterpret_cast<const f32x4*>(src + 4);
        *reinterpret_cast<bf16x8*>(Abf + (size_t)bid * K_TOT + c8) = cvt8(v0, v1);
    } else {
        const int r  = bid - B_ROWS;       // 0..4095
        const int bh = r >> 8;
        const int n  = r & 255;
        const int g  = (n >> 4) & 3;
        const int j  = (n >> 6) * 16 + (n & 15);
        const int wr = g * H_DIM + bh * 64 + j;
        const float* src = (c8 < IN_DIM)
            ? (W_ih + (size_t)wr * IN_DIM + c8)
            : (W_hh + (size_t)wr * IN_DIM + (c8 - IN_DIM));
        f32x4 v0 = *reinterpret_cast<const f32x4*>(src);
        f32x4 v1 = *reinterpret_cast<const f32x4*>(src + 4);
        *reinterpret_cast<bf16x8*>(Wp + (size_t)r * K_TOT + c8) = cvt8(v0, v1);
    }
}

// stage one 128x64 half-tile: 2 x global_load_lds(16B)/thread, linear LDS dest,
// inverse-swizzled global source.
__device__ __forceinline__ void stage_half(const __bf16* __restrict__ gbase, int kb,
                                           __bf16* lbase, int row0, int tid) {
    #pragma unroll
    for (int i = 0; i < 2; ++i) {
        int e   = i * 4096 + tid * 8;
        int row = row0 + (e >> 6);
        int kd  = e & 63;
        gload16(gbase + (size_t)row * K_TOT + kb + (kd ^ ((row & 7) << 3)), lbase + e);
    }
}

#define SWZ(r, k) ((r) * 64 + ((k) ^ (((r) & 7) << 3)))

#define LDB(Bs) { \
    _Pragma("unroll") \
    for (int fn = 0; fn < 4; ++fn) { \
        int br = wcol + fn * 16 + lr; \
        bfr[fn][0] = *reinterpret_cast<const bf16x8*>(&(Bs)[SWZ(br, lh * 8)]); \
        bfr[fn][1] = *reinterpret_cast<const bf16x8*>(&(Bs)[SWZ(br, 32 + lh * 8)]); \
    } }

#define LDA(As, q) { \
    int ar = wrow + (q) * 32 + lr; \
    af[0][0] = *reinterpret_cast<const bf16x8*>(&(As)[SWZ(ar, lh * 8)]); \
    af[0][1] = *reinterpret_cast<const bf16x8*>(&(As)[SWZ(ar, 32 + lh * 8)]); \
    af[1][0] = *reinterpret_cast<const bf16x8*>(&(As)[SWZ(ar + 16, lh * 8)]); \
    af[1][1] = *reinterpret_cast<const bf16x8*>(&(As)[SWZ(ar + 16, 32 + lh * 8)]); \
    }

// one barrier per phase: wave's frag reads complete (lgkm0) BEFORE the barrier,
// so the next phase's stage may overwrite the read region safely.
#define WBAR \
    asm volatile("s_waitcnt lgkmcnt(0)" ::: "memory"); \
    __builtin_amdgcn_sched_barrier(0); \
    __builtin_amdgcn_s_barrier(); \
    __builtin_amdgcn_sched_barrier(0);

#define WBARV \
    asm volatile("s_waitcnt lgkmcnt(0)" ::: "memory"); \
    asm volatile("s_waitcnt vmcnt(4)"   ::: "memory"); \
    __builtin_amdgcn_sched_barrier(0); \
    __builtin_amdgcn_s_barrier(); \
    __builtin_amdgcn_sched_barrier(0);

// k-slice-outer ordering: 8 independent MFMAs between dependent same-acc pairs
#define MF(q) { \
    __builtin_amdgcn_s_setprio(1); \
    _Pragma("unroll") \
    for (int ks = 0; ks < 2; ++ks) { \
        _Pragma("unroll") \
        for (int fn = 0; fn < 4; ++fn) { \
            acc[2*(q)][fn]   = __builtin_amdgcn_mfma_f32_16x16x32_bf16(af[0][ks], bfr[fn][ks], acc[2*(q)][fn],   0,0,0); \
            acc[2*(q)+1][fn] = __builtin_amdgcn_mfma_f32_16x16x32_bf16(af[1][ks], bfr[fn][ks], acc[2*(q)+1][fn], 0,0,0); \
        } \
    } \
    __builtin_amdgcn_s_setprio(0); \
    __builtin_amdgcn_sched_barrier(0); \
}

__global__ __launch_bounds__(THREADS, 2)
void onlstm_gemm8(const __bf16* __restrict__ Abf, const __bf16* __restrict__ Wp,
                  const float* __restrict__ cx,
                  const float* __restrict__ input_floor,
                  const float* __restrict__ forget_floor,
                  const float* __restrict__ b_ih, const float* __restrict__ b_hh,
                  float* __restrict__ out)
{
    __shared__ __align__(16) __bf16 lds[65536];          // 128 KiB
    __shared__ float ci_s[BM], cf_s[BM], bias_s[BN];

    const int tid = threadIdx.x;
    // XCD swizzle: xcd = n0&7 owns bm in [4*xcd, 4*xcd+4) x all 16 bh
    // -> A working set 4 panels = 4 MiB = L2-resident per XCD.
    const int n0  = blockIdx.x;
    const int bm  = (n0 & 7) * 4 + ((n0 >> 3) & 3);   // 0..31
    const int bh  = n0 >> 5;                          // 0..15
    const int h0  = bh * 64;
    const int nc  = bh;

    // ---- prologue: bias + per-row cumulative-softmax master gates ----
    if (tid < BM) {
        {
            int g = (tid >> 4) & 3;
            int j = (tid >> 6) * 16 + (tid & 15);
            int wrr = g * H_DIM + h0 + j;
            bias_s[tid] = b_ih[wrr] + b_hh[wrr];
        }
        int b = bm * BM + tid;
        const int off = (nc < 8) ? 0 : 8;
        const int ic  = (nc < 8) ? nc : (nc - 8);
        const float* pin = input_floor  + (size_t)b * NCHUNK + off;
        const float* pfg = forget_floor + (size_t)b * NCHUNK + off;
        float vi[8], vf[8];
        float mi = -1e30f, mf = -1e30f;
        #pragma unroll
        for (int t = 0; t < 8; ++t) {
            vi[t] = pin[t]; vf[t] = pfg[t];
            mi = fmaxf(mi, vi[t]); mf = fmaxf(mf, vf[t]);
        }
        float si = 0.f, sf = 0.f;
        #pragma unroll
        for (int t = 0; t < 8; ++t) {
            vi[t] = __expf(vi[t] - mi); vf[t] = __expf(vf[t] - mf);
            si += vi[t]; sf += vf[t];
        }
        float pi = 0.f, pf = 0.f;
        #pragma unroll
        for (int t = 0; t < 8; ++t) { if (t <= ic) { pi += vi[t]; pf += vf[t]; } }
        float suf_i = si - pi + vi[ic];
        float suf_f = sf - pf + vf[ic];
        float civ, cfv;
        if (nc < 8) { civ = pi / si;    cfv = suf_f / sf; }
        else        { civ = suf_i / si; cfv = pf / sf;    }
        ci_s[tid] = civ; cf_s[tid] = cfv;
    }

    const __bf16* Arow = Abf + (size_t)(bm * BM) * K_TOT;
    const __bf16* Wblk = Wp  + (size_t)bh * 256 * K_TOT;
    __bf16* const A0p = lds;
    __bf16* const B0p = lds + 16384;
    __bf16* const A1p = lds + 32768;
    __bf16* const B1p = lds + 49152;

    // prologue staging: t0.A (A0p), t0.B (B0p), t1.B (B1p); t1.A staged at t0.p0
    stage_half(Arow, 0,  A0p,        0,   tid);
    stage_half(Arow, 0,  A0p + 8192, 128, tid);
    stage_half(Wblk, 0,  B0p,        0,   tid);
    stage_half(Wblk, 0,  B0p + 8192, 128, tid);
    stage_half(Wblk, BK, B1p,        0,   tid);
    stage_half(Wblk, BK, B1p + 8192, 128, tid);
    asm volatile("s_waitcnt lgkmcnt(0)" ::: "memory");   // ci/bias ds_writes done
    asm volatile("s_waitcnt vmcnt(4)"   ::: "memory");   // t0 complete, t1.B in flight
    __builtin_amdgcn_s_barrier();
    asm volatile("" ::: "memory");

    f32x4  acc[8][4];
    #pragma unroll
    for (int i = 0; i < 8; ++i)
        #pragma unroll
        for (int j = 0; j < 4; ++j) acc[i][j] = (f32x4){0.f, 0.f, 0.f, 0.f};
    bf16x8 af[2][2];
    bf16x8 bfr[4][2];

    const int l    = tid & 63;
    const int wid  = tid >> 6;        // 0..7
    const int wrw  = wid >> 2;        // 0..1  (M)
    const int wc   = wid & 3;         // 0..3  (N)
    const int lr   = l & 15;
    const int lh   = l >> 4;
    const int wrow = wrw * 128;
    const int wcol = wc * 64;

    #pragma unroll 1
    for (int it = 0; it < NKT / 2; ++it) {
        const int t = 2 * it;
        // ---- K-tile t (buf0) ----
        LDB(B0p); LDA(A0p, 0);
        stage_half(Arow, ((t + 1) & 31) * BK, A1p,        0,   tid);   // (t+1).A0
        stage_half(Arow, ((t + 1) & 31) * BK, A1p + 8192, 128, tid);   // (t+1).A1
        WBAR; MF(0);
        LDA(A0p, 1);
        stage_half(Wblk, ((t + 2) & 31) * BK, B0p,        0,   tid);   // (t+2).B0
        WBAR; MF(1);
        LDA(A0p, 2);
        stage_half(Wblk, ((t + 2) & 31) * BK, B0p + 8192, 128, tid);   // (t+2).B1
        WBAR; MF(2);
        LDA(A0p, 3);
        WBARV; MF(3);
        // ---- K-tile t+1 (buf1) ----
        LDB(B1p); LDA(A1p, 0);
        stage_half(Arow, ((t + 2) & 31) * BK, A0p,        0,   tid);   // (t+2).A0
        stage_half(Arow, ((t + 2) & 31) * BK, A0p + 8192, 128, tid);   // (t+2).A1
        WBAR; MF(0);
        LDA(A1p, 1);
        stage_half(Wblk, ((t + 3) & 31) * BK, B1p,        0,   tid);   // (t+3).B0
        WBAR; MF(1);
        LDA(A1p, 2);
        stage_half(Wblk, ((t + 3) & 31) * BK, B1p + 8192, 128, tid);   // (t+3).B1
        WBAR; MF(2);
        LDA(A1p, 3);
        WBARV; MF(3);
    }
    asm volatile("s_waitcnt vmcnt(0)" ::: "memory");
    __builtin_amdgcn_s_barrier();

    // ---- epilogue: all 4 gates of (b,h) lane-local (fn = gate) ----
    const size_t CY_OFF = (size_t)B_ROWS * H_DIM;
    const int hcol = h0 + wc * 16 + lr;
    #pragma unroll
    for (int m = 0; m < 8; ++m) {
        #pragma unroll
        for (int r = 0; r < 4; ++r) {
            int rt = wrow + m * 16 + lh * 4 + r;
            int b  = bm * BM + rt;
            float civ = ci_s[rt], cfv = cf_s[rt];
            float ovl = cfv * civ;
            float og = acc[m][0][r] + bias_s[wcol + lr];
            float cg = acc[m][1][r] + bias_s[wcol + 16 + lr];
            float ig = acc[m][2][r] + bias_s[wcol + 32 + lr];
            float fg = acc[m][3][r] + bias_s[wcol + 48 + lr];
            float i_s = sigmoidf_(ig);
            float f_s = sigmoidf_(fg);
            float c_t = tanhf_(cg);
            float o_s = sigmoidf_(og);
            float fq = f_s * ovl + (cfv - ovl);
            float iq = i_s * ovl + (civ - ovl);
            float cxv = cx[(size_t)b * H_DIM + hcol];
            float cyv = fq * cxv + iq * c_t;
            float hyv = o_s * tanhf_(cyv);
            out[(size_t)b * H_DIM + hcol] = hyv;
            out[CY_OFF + (size_t)b * H_DIM + hcol] = cyv;
        }
    }
}

extern "C" void kernel_launch(void* const* d_in, const int* in_sizes, int n_in,
                              void* d_out, int out_size, void* d_ws, size_t ws_size,
                              hipStream_t stream) {
    const float* x            = (const float*)d_in[0];
    const float* hx           = (const float*)d_in[1];
    const float* cx           = (const float*)d_in[2];
    const float* input_floor  = (const float*)d_in[3];
    const float* forget_floor = (const float*)d_in[4];
    const float* W_ih         = (const float*)d_in[5];
    const float* b_ih         = (const float*)d_in[6];
    const float* W_hh         = (const float*)d_in[7];
    const float* b_hh         = (const float*)d_in[8];
    float* out = (float*)d_out;

    __bf16* Abf = (__bf16*)d_ws;
    __bf16* Wp  = (__bf16*)((char*)d_ws + A_PACK_BYTES);
    pack_AW<<<B_ROWS + 16 * 256, 256, 0, stream>>>(x, hx, W_ih, W_hh, Abf, Wp);
    onlstm_gemm8<<<512, THREADS, 0, stream>>>(
        Abf, Wp, cx, input_floor, forget_floor, b_ih, b_hh, out);
}